// Round 17
// baseline (185.649 us; speedup 1.0000x reference)
//
#include <hip/hip_runtime.h>
#include <math.h>

// TiSASRec forward on MI355X — round 16:
//  - Base: R15 (best measured: 179.4us; attn 45.3us, bf16 Qt).
//  - Single change: ALL 1600-block kernels (ln_qkv, attn, mid, end) share
//    the same block->rows mapping {i,99-i,100+i,199-i}. Under round-robin
//    blockIdx->XCD dispatch, the producer and consumer of each Qt/Q/K/V/att
//    row land on the SAME XCD -> per-XCD L2 (4MB) can serve the 1.2MB/XCD
//    Qt slice instead of ~900cy HBM-latency misses. Zero instruction change;
//    attn kernel body byte-identical to R15.
// B=32, L=200, D=64, H=2, dh=32, NL=2.
#define BB 32
#define LLEN 200
#define DD 64
#define HH 2
#define NLAYER 2
#define BLD (BB * LLEN * DD)
#define TSPAN1 366   // TIME_SPAN+1
#define QTROW (2 * TSPAN1)   // 732 bf16 per row

__device__ inline float waveSum(float v) {
#pragma unroll
    for (int off = 32; off > 0; off >>= 1) v += __shfl_xor(v, off);
    return v;
}
__device__ inline float halfSum(float v) {
    v += __shfl_xor(v, 1);
    v += __shfl_xor(v, 2);
    v += __shfl_xor(v, 4);
    v += __shfl_xor(v, 8);
    v += __shfl_xor(v, 16);
    return v;
}
__device__ inline float halfMax(float v) {
    v = fmaxf(v, __shfl_xor(v, 1));
    v = fmaxf(v, __shfl_xor(v, 2));
    v = fmaxf(v, __shfl_xor(v, 4));
    v = fmaxf(v, __shfl_xor(v, 8));
    v = fmaxf(v, __shfl_xor(v, 16));
    return v;
}

// f32 -> bf16 with round-to-nearest-even
__device__ inline unsigned short f2bf(float f) {
    unsigned u = __float_as_uint(f);
    u = (u + 0x7FFFu + ((u >> 16) & 1u)) >> 16;
    return (unsigned short)u;
}
__device__ inline float bf2f(unsigned short b) {
    return __uint_as_float(((unsigned)b) << 16);
}

// shared block->query mapping: block u, wave w -> query qi within batch bi
__device__ inline int qsel_of(int i, int w) {
    return (w == 0) ? i : (w == 1) ? (99 - i) : (w == 2) ? (100 + i) : (199 - i);
}

// qt tail: thread t owns bucket t (coalesced tKT column reads);
// Qt[rows.w][h*366+t] = Qsh[w] . tK[t] (head h), stored bf16.
__device__ inline void qt_tail(const float (*Qsh)[DD], const float* __restrict__ tKT,
                               unsigned short* __restrict__ Qt_g, int4 rows) {
    int tid = threadIdx.x;
    for (int t = tid; t < TSPAN1; t += 256) {
        const float* tk = tKT + t;
        float a0 = 0, a1 = 0, a2 = 0, a3 = 0;
#pragma unroll 8
        for (int d = 0; d < 32; ++d) {
            float v = tk[d * TSPAN1];
            a0 = fmaf(v, Qsh[0][d], a0);
            a1 = fmaf(v, Qsh[1][d], a1);
            a2 = fmaf(v, Qsh[2][d], a2);
            a3 = fmaf(v, Qsh[3][d], a3);
        }
        Qt_g[(size_t)rows.x * QTROW + t] = f2bf(a0);
        Qt_g[(size_t)rows.y * QTROW + t] = f2bf(a1);
        Qt_g[(size_t)rows.z * QTROW + t] = f2bf(a2);
        Qt_g[(size_t)rows.w * QTROW + t] = f2bf(a3);
        float b0 = 0, b1 = 0, b2 = 0, b3 = 0;
#pragma unroll 8
        for (int d = 32; d < 64; ++d) {
            float v = tk[d * TSPAN1];
            b0 = fmaf(v, Qsh[0][d], b0);
            b1 = fmaf(v, Qsh[1][d], b1);
            b2 = fmaf(v, Qsh[2][d], b2);
            b3 = fmaf(v, Qsh[3][d], b3);
        }
        Qt_g[(size_t)rows.x * QTROW + TSPAN1 + t] = f2bf(b0);
        Qt_g[(size_t)rows.y * QTROW + TSPAN1 + t] = f2bf(b1);
        Qt_g[(size_t)rows.z * QTROW + TSPAN1 + t] = f2bf(b2);
        Qt_g[(size_t)rows.w * QTROW + TSPAN1 + t] = f2bf(b3);
    }
}

// grid=11: m<10 -> transpose 64x64 weights; m==10 -> tK_emb^T [64][366]
__global__ void transpose_kernel(const float* __restrict__ Wq,
                                 const float* __restrict__ Wk,
                                 const float* __restrict__ Wv,
                                 const float* __restrict__ W1,
                                 const float* __restrict__ W2,
                                 const float* __restrict__ tK_emb,
                                 float* __restrict__ wt,
                                 float* __restrict__ tKT) {
    int m = blockIdx.x;
    if (m < 10) {
        const float* src;
        switch (m % 5) {
            case 0: src = Wq; break;
            case 1: src = Wk; break;
            case 2: src = Wv; break;
            case 3: src = W1; break;
            default: src = W2; break;
        }
        src += (m / 5) * DD * DD;
        float* dst = wt + m * DD * DD;
        for (int e = threadIdx.x; e < DD * DD; e += 256) {
            int d = e >> 6, j = e & 63;
            dst[j * DD + d] = src[e];
        }
    } else {
        for (int e = threadIdx.x; e < TSPAN1 * DD; e += 256) {
            int t = e >> 6, d = e & 63;
            tKT[d * TSPAN1 + t] = tK_emb[e];
        }
    }
}

// Layer-0 entry + fused qt: block u owns rows {i,99-i,100+i,199-i} of batch
// bi (u=bi*50+i) — the SAME rows attn block u consumes (XCD locality).
__global__ void ln_qkv_kernel(const int* __restrict__ log_ids,
                              const float* __restrict__ item_emb,
                              const float* __restrict__ g,
                              const float* __restrict__ bln,
                              const float* __restrict__ WqT, const float* __restrict__ bq,
                              const float* __restrict__ WkT, const float* __restrict__ bk,
                              const float* __restrict__ WvT, const float* __restrict__ bv,
                              const float* __restrict__ posK,
                              const float* __restrict__ posV,
                              const float* __restrict__ tKT,
                              float* __restrict__ q,
                              float* __restrict__ Q, float* __restrict__ K,
                              float* __restrict__ V,
                              unsigned short* __restrict__ Qt_g) {
    __shared__ float qs[4][DD], xs[4][DD], Qsh[4][DD];
    int tid = threadIdx.x;
    int wid = tid >> 6, d = tid & 63;
    int bi = blockIdx.x / 50, i = blockIdx.x % 50;
    int l = qsel_of(i, wid);
    int row = bi * LLEN + l;
    int id = log_ids[row];
    float xv = (id == 0) ? 0.0f : item_emb[(size_t)id * DD + d] * 8.0f;  // sqrt(64)*keep
    xs[wid][d] = xv;
    float m = waveSum(xv) * (1.0f / 64.0f);
    float c = xv - m;
    float var = waveSum(c * c) * (1.0f / 64.0f);
    float qv = (c / sqrtf(var + 1e-8f)) * g[d] + bln[d];
    qs[wid][d] = qv;
    q[(size_t)row * DD + d] = qv;
    float aq = bq[d], ak = bk[d], av = bv[d];
#pragma unroll 8
    for (int j = 0; j < DD; ++j) {
        aq = fmaf(qs[wid][j], WqT[j * DD + d], aq);
        ak = fmaf(xs[wid][j], WkT[j * DD + d], ak);
        av = fmaf(xs[wid][j], WvT[j * DD + d], av);
    }
    Q[(size_t)row * DD + d] = aq;
    K[(size_t)row * DD + d] = ak + posK[l * DD + d];
    V[(size_t)row * DD + d] = av + posV[l * DD + d];
    Qsh[wid][d] = aq;
    __syncthreads();
    int4 rows;
    rows.x = bi * LLEN + qsel_of(i, 0);
    rows.y = bi * LLEN + qsel_of(i, 1);
    rows.z = bi * LLEN + qsel_of(i, 2);
    rows.w = bi * LLEN + qsel_of(i, 3);
    qt_tail(Qsh, tKT, Qt_g, rows);
}

// Attention (R15-exact body). wave-per-query {i,99-i,100+i,199-i};
// per-wave phases; qt_s staged (bf16, uint2 loads); 4-key score groups.
__global__ void attn_kernel(const float* __restrict__ Q,
                            const float* __restrict__ Keff,
                            const float* __restrict__ Veff,
                            const int* __restrict__ log_times,
                            const unsigned short* __restrict__ Qt_g,
                            const float* __restrict__ tV_emb,
                            float* __restrict__ out) {
    __shared__ int t_s[LLEN];
    __shared__ float sc[4][HH][LLEN];
    __shared__ unsigned short tm_s[4][LLEN];
    __shared__ __align__(8) unsigned short qt_s[4][QTROW];

    int tid = threadIdx.x;
    int wid = tid >> 6;
    int lane = tid & 63;
    int bi = blockIdx.x / 50;
    int i = blockIdx.x % 50;
    int qi = qsel_of(i, wid);
    int row = bi * LLEN + qi;
    int len = qi + 1;

    if (tid < LLEN) t_s[tid] = log_times[bi * LLEN + tid];
    __syncthreads();

    // stage this query's Qt row (732 bf16 = 183 uint2) into LDS
    {
        const uint2* qtrow2 = (const uint2*)(Qt_g + (size_t)row * QTROW);
        uint2* qts2 = (uint2*)&qt_s[wid][0];
        for (int e = lane; e < 183; e += 64) qts2[e] = qtrow2[e];
    }

    // bucket table for this query
    int tq = t_s[qi];
    for (int k = lane; k < len; k += 64) {
        int dt = tq - t_s[k];
        if (dt < 0) dt = -dt;
        float dtf = fminf((float)dt * (1.0f / 86400.0f), 365.0f);
        tm_s[wid][k] = (unsigned short)(int)dtf;
    }

    int h = lane >> 5;       // head
    int l5 = lane & 31;
    int cch = l5 >> 2;       // channel chunk 0..7
    int jo = l5 & 3;         // key offset in group
    float4 qv = ((const float4*)(Q + (size_t)row * DD))[h * 8 + cch];
    const float4* K4 = (const float4*)(Keff + (size_t)bi * LLEN * DD);
    const float scale = 0.17677669529663687f;  // 1/sqrt(32)

    // phase 1: scores, 4 keys per iteration
    for (int k0 = 0; k0 < len; k0 += 4) {
        int k = k0 + jo;
        int kc = (k < len) ? k : (len - 1);
        int bucket = tm_s[wid][kc];
        float4 kv = K4[kc * 16 + h * 8 + cch];
        float p = qv.x * kv.x + qv.y * kv.y + qv.z * kv.z + qv.w * kv.w;
        p += __shfl_xor(p, 4);
        p += __shfl_xor(p, 8);
        p += __shfl_xor(p, 16);   // full 32-dot for (h, key k)
        float s = (p + bf2f(qt_s[wid][h * TSPAN1 + bucket])) * scale;
        if (cch == 0 && k < len) sc[wid][h][k] = s;
    }

    // phase 2: softmax (lanes 0..31 head 0, 32..63 head 1; same wave)
    {
        float m = -INFINITY;
        for (int k = l5; k < len; k += 32) m = fmaxf(m, sc[wid][h][k]);
        m = halfMax(m);
        float s = 0.0f;
        for (int k = l5; k < len; k += 32) {
            float e = expf(sc[wid][h][k] - m);
            sc[wid][h][k] = e;
            s += e;
        }
        s = halfSum(s);
        float inv = 1.0f / s;
        for (int k = l5; k < len; k += 32) sc[wid][h][k] *= inv;
    }

    // phase 3: out[d] = sum_k A[h][k] * (V_eff[k][d] + tV[bucket[k]][d])
    const float* Vb = Veff + (size_t)bi * LLEN * DD + lane;
    const float* tVl = tV_emb + lane;
    float acc0 = 0.0f, acc1 = 0.0f, acc2 = 0.0f, acc3 = 0.0f;
    int k = 0;
    for (; k + 4 <= len; k += 4) {
        int b0 = tm_s[wid][k + 0];
        int b1 = tm_s[wid][k + 1];
        int b2 = tm_s[wid][k + 2];
        int b3 = tm_s[wid][k + 3];
        float a0 = sc[wid][h][k + 0];
        float a1 = sc[wid][h][k + 1];
        float a2 = sc[wid][h][k + 2];
        float a3 = sc[wid][h][k + 3];
        acc0 = fmaf(a0, Vb[(k + 0) * DD] + tVl[b0 * DD], acc0);
        acc1 = fmaf(a1, Vb[(k + 1) * DD] + tVl[b1 * DD], acc1);
        acc2 = fmaf(a2, Vb[(k + 2) * DD] + tVl[b2 * DD], acc2);
        acc3 = fmaf(a3, Vb[(k + 3) * DD] + tVl[b3 * DD], acc3);
    }
    for (; k < len; ++k) {
        int b0 = tm_s[wid][k];
        acc0 = fmaf(sc[wid][h][k], Vb[k * DD] + tVl[b0 * DD], acc0);
    }
    out[(size_t)row * DD + lane] = (acc0 + acc1) + (acc2 + acc3);
}

// MID + fused qt: same balanced block->rows mapping as attn (XCD locality
// for att/q reads and Qt/Q/K/V writes).
__global__ void mid_kernel(const float* __restrict__ qin,
                           const float* __restrict__ att,
                           const float* __restrict__ g2, const float* __restrict__ b2ln,
                           const float* __restrict__ W1T, const float* __restrict__ b1v,
                           const float* __restrict__ W2T, const float* __restrict__ b2v,
                           const int* __restrict__ log_ids,
                           const float* __restrict__ g1n, const float* __restrict__ b1n,
                           const float* __restrict__ WqT, const float* __restrict__ bq,
                           const float* __restrict__ WkT, const float* __restrict__ bk,
                           const float* __restrict__ WvT, const float* __restrict__ bv,
                           const float* __restrict__ posK,
                           const float* __restrict__ posV,
                           const float* __restrict__ tKT,
                           float* __restrict__ q,
                           float* __restrict__ Q, float* __restrict__ K,
                           float* __restrict__ V,
                           unsigned short* __restrict__ Qt_g) {
    __shared__ float xs[4][DD], hs[4][DD], qs[4][DD], Qsh[4][DD];
    int tid = threadIdx.x;
    int wid = tid >> 6, d = tid & 63;
    int bi = blockIdx.x / 50, i = blockIdx.x % 50;
    int l = qsel_of(i, wid);
    int row = bi * LLEN + l;
    // --- addln + FFN ---
    float v = qin[(size_t)row * DD + d] + att[(size_t)row * DD + d];
    float m = waveSum(v) * (1.0f / 64.0f);
    float c = v - m;
    float var = waveSum(c * c) * (1.0f / 64.0f);
    float xv = (c / sqrtf(var + 1e-8f)) * g2[d] + b2ln[d];
    xs[wid][d] = xv;
    float a = b1v[d];
#pragma unroll 8
    for (int j = 0; j < DD; ++j) a = fmaf(xs[wid][j], W1T[j * DD + d], a);
    hs[wid][d] = fmaxf(a, 0.0f);
    float o = b2v[d];
#pragma unroll 8
    for (int j = 0; j < DD; ++j) o = fmaf(hs[wid][j], W2T[j * DD + d], o);
    float res = xv + o;
    if (log_ids[row] == 0) res = 0.0f;
    // --- next layer: LN1 + QKV projection ---
    float m2 = waveSum(res) * (1.0f / 64.0f);
    float c2 = res - m2;
    float var2 = waveSum(c2 * c2) * (1.0f / 64.0f);
    float qv = (c2 / sqrtf(var2 + 1e-8f)) * g1n[d] + b1n[d];
    qs[wid][d] = qv;
    xs[wid][d] = res;
    q[(size_t)row * DD + d] = qv;
    float aq = bq[d], ak = bk[d], av = bv[d];
#pragma unroll 8
    for (int j = 0; j < DD; ++j) {
        aq = fmaf(qs[wid][j], WqT[j * DD + d], aq);
        ak = fmaf(xs[wid][j], WkT[j * DD + d], ak);
        av = fmaf(xs[wid][j], WvT[j * DD + d], av);
    }
    Q[(size_t)row * DD + d] = aq;
    K[(size_t)row * DD + d] = ak + posK[l * DD + d];
    V[(size_t)row * DD + d] = av + posV[l * DD + d];
    Qsh[wid][d] = aq;
    __syncthreads();
    int4 rows;
    rows.x = bi * LLEN + qsel_of(i, 0);
    rows.y = bi * LLEN + qsel_of(i, 1);
    rows.z = bi * LLEN + qsel_of(i, 2);
    rows.w = bi * LLEN + qsel_of(i, 3);
    qt_tail(Qsh, tKT, Qt_g, rows);
}

// END: addln_ffn(last layer) + final LN + logits; same mapping (att/q local).
__global__ void end_kernel(const float* __restrict__ qin,
                           const float* __restrict__ att,
                           const float* __restrict__ g2, const float* __restrict__ b2ln,
                           const float* __restrict__ W1T, const float* __restrict__ b1v,
                           const float* __restrict__ W2T, const float* __restrict__ b2v,
                           const int* __restrict__ log_ids,
                           const float* __restrict__ lnf_g, const float* __restrict__ lnf_b,
                           const float* __restrict__ item_emb,
                           const int* __restrict__ pos_ids,
                           const int* __restrict__ neg_ids,
                           float* __restrict__ out) {
    __shared__ float xs[4][DD], hs[4][DD];
    int tid = threadIdx.x;
    int wid = tid >> 6, d = tid & 63;
    int bi = blockIdx.x / 50, i = blockIdx.x % 50;
    int row = bi * LLEN + qsel_of(i, wid);
    float v = qin[(size_t)row * DD + d] + att[(size_t)row * DD + d];
    float m = waveSum(v) * (1.0f / 64.0f);
    float c = v - m;
    float var = waveSum(c * c) * (1.0f / 64.0f);
    float xv = (c / sqrtf(var + 1e-8f)) * g2[d] + b2ln[d];
    xs[wid][d] = xv;
    float a = b1v[d];
#pragma unroll 8
    for (int j = 0; j < DD; ++j) a = fmaf(xs[wid][j], W1T[j * DD + d], a);
    hs[wid][d] = fmaxf(a, 0.0f);
    float o = b2v[d];
#pragma unroll 8
    for (int j = 0; j < DD; ++j) o = fmaf(hs[wid][j], W2T[j * DD + d], o);
    float res = xv + o;
    if (log_ids[row] == 0) res = 0.0f;
    // --- final LN + logits ---
    float m2 = waveSum(res) * (1.0f / 64.0f);
    float c2 = res - m2;
    float var2 = waveSum(c2 * c2) * (1.0f / 64.0f);
    float f = (c2 / sqrtf(var2 + 1e-8f)) * lnf_g[d] + lnf_b[d];
    int pid = pos_ids[row];
    int nid = neg_ids[row];
    float p = waveSum(f * item_emb[(size_t)pid * DD + d]);
    float n = waveSum(f * item_emb[(size_t)nid * DD + d]);
    if (d == 0) {
        out[row] = p;
        out[BB * LLEN + row] = n;
    }
}

extern "C" void kernel_launch(void* const* d_in, const int* in_sizes, int n_in,
                              void* d_out, int out_size, void* d_ws, size_t ws_size,
                              hipStream_t stream) {
    const int* log_ids = (const int*)d_in[0];
    const int* log_times = (const int*)d_in[1];
    const int* pos_ids = (const int*)d_in[2];
    const int* neg_ids = (const int*)d_in[3];
    const float* item_emb = (const float*)d_in[4];
    const float* posK = (const float*)d_in[5];
    const float* posV = (const float*)d_in[6];
    const float* tK_emb = (const float*)d_in[7];
    const float* tV_emb = (const float*)d_in[8];
    const float* ln1_g = (const float*)d_in[9];
    const float* ln1_b = (const float*)d_in[10];
    const float* Wq = (const float*)d_in[11];
    const float* bq = (const float*)d_in[12];
    const float* Wk = (const float*)d_in[13];
    const float* bk = (const float*)d_in[14];
    const float* Wv = (const float*)d_in[15];
    const float* bv = (const float*)d_in[16];
    const float* ln2_g = (const float*)d_in[17];
    const float* ln2_b = (const float*)d_in[18];
    const float* W1 = (const float*)d_in[19];
    const float* b1 = (const float*)d_in[20];
    const float* W2 = (const float*)d_in[21];
    const float* b2 = (const float*)d_in[22];
    const float* lnf_g = (const float*)d_in[23];
    const float* lnf_b = (const float*)d_in[24];

    float* ws = (float*)d_ws;
    float* q = ws;                        // ln1 output (residual)
    float* Qb = q + BLD;
    float* Kb = Qb + BLD;
    float* Vb = Kb + BLD;
    float* att = Vb + BLD;
    float* wt = att + BLD;                // 10 x 64x64 transposed weights
    float* tKT = wt + 10 * DD * DD;       // [64][366]
    unsigned short* Qt = (unsigned short*)(tKT + DD * TSPAN1);  // [6400][732] bf16

    const int nrow = BB * LLEN;           // 6400

    const float* W1T0 = wt + 3 * DD * DD;
    const float* W2T0 = wt + 4 * DD * DD;
    const float* W1T1 = wt + 8 * DD * DD;
    const float* W2T1 = wt + 9 * DD * DD;

    transpose_kernel<<<11, 256, 0, stream>>>(Wq, Wk, Wv, W1, W2, tK_emb, wt, tKT);

    // layer 0 entry (embed + qt fused)
    ln_qkv_kernel<<<nrow / 4, 256, 0, stream>>>(log_ids, item_emb,
                                                ln1_g, ln1_b,
                                                wt + 0 * DD * DD, bq,
                                                wt + 1 * DD * DD, bk,
                                                wt + 2 * DD * DD, bv,
                                                posK, posV, tKT,
                                                q, Qb, Kb, Vb, Qt);
    attn_kernel<<<BB * 50, 256, 0, stream>>>(Qb, Kb, Vb, log_times, Qt, tV_emb, att);

    // layer 0 tail + layer 1 entry (+ qt fused)
    mid_kernel<<<nrow / 4, 256, 0, stream>>>(q, att,
                                             ln2_g, ln2_b,
                                             W1T0, b1, W2T0, b2,
                                             log_ids,
                                             ln1_g + DD, ln1_b + DD,
                                             wt + 5 * DD * DD, bq + DD,
                                             wt + 6 * DD * DD, bk + DD,
                                             wt + 7 * DD * DD, bv + DD,
                                             posK, posV, tKT,
                                             q, Qb, Kb, Vb, Qt);
    attn_kernel<<<BB * 50, 256, 0, stream>>>(Qb, Kb, Vb, log_times, Qt, tV_emb, att);

    // layer 1 tail + final logits
    end_kernel<<<nrow / 4, 256, 0, stream>>>(q, att,
                                             ln2_g + DD, ln2_b + DD,
                                             W1T1, b1 + DD, W2T1, b2 + DD,
                                             log_ids,
                                             lnf_g, lnf_b, item_emb,
                                             pos_ids, neg_ids, (float*)d_out);
}

// Round 18
// 179.690 us; speedup vs baseline: 1.0332x; 1.0332x over previous
//
#include <hip/hip_runtime.h>
#include <math.h>

// TiSASRec forward on MI355X — round 17: R15 byte-exact resubmission.
//  - R16 post-mortem: "zero-cost" qsel_of index refactor perturbed codegen
//    (attn VGPR 28->20) and regressed attn 45.3->48.8us; FETCH unchanged
//    => no XCD-locality gain. Reverted.
//  - R15 config: R9 structure + bf16 Qt table (best measured: 179.4us).
// B=32, L=200, D=64, H=2, dh=32, NL=2.
#define BB 32
#define LLEN 200
#define DD 64
#define HH 2
#define NLAYER 2
#define BLD (BB * LLEN * DD)
#define TSPAN1 366   // TIME_SPAN+1
#define QTROW (2 * TSPAN1)   // 732 bf16 per row

__device__ inline float waveSum(float v) {
#pragma unroll
    for (int off = 32; off > 0; off >>= 1) v += __shfl_xor(v, off);
    return v;
}
__device__ inline float halfSum(float v) {
    v += __shfl_xor(v, 1);
    v += __shfl_xor(v, 2);
    v += __shfl_xor(v, 4);
    v += __shfl_xor(v, 8);
    v += __shfl_xor(v, 16);
    return v;
}
__device__ inline float halfMax(float v) {
    v = fmaxf(v, __shfl_xor(v, 1));
    v = fmaxf(v, __shfl_xor(v, 2));
    v = fmaxf(v, __shfl_xor(v, 4));
    v = fmaxf(v, __shfl_xor(v, 8));
    v = fmaxf(v, __shfl_xor(v, 16));
    return v;
}

// f32 -> bf16 with round-to-nearest-even
__device__ inline unsigned short f2bf(float f) {
    unsigned u = __float_as_uint(f);
    u = (u + 0x7FFFu + ((u >> 16) & 1u)) >> 16;
    return (unsigned short)u;
}
__device__ inline float bf2f(unsigned short b) {
    return __uint_as_float(((unsigned)b) << 16);
}

// qt tail (R9 structure): thread t owns bucket t (coalesced tKT column
// reads); Qt[row][h*366+t] = Qsh[r] . tK[t] (head h), stored bf16.
__device__ inline void qt_tail(const float (*Qsh)[DD], const float* __restrict__ tKT,
                               unsigned short* __restrict__ Qt_g, int base) {
    int tid = threadIdx.x;
    for (int t = tid; t < TSPAN1; t += 256) {
        const float* tk = tKT + t;
        float a0 = 0, a1 = 0, a2 = 0, a3 = 0;
#pragma unroll 8
        for (int d = 0; d < 32; ++d) {
            float v = tk[d * TSPAN1];
            a0 = fmaf(v, Qsh[0][d], a0);
            a1 = fmaf(v, Qsh[1][d], a1);
            a2 = fmaf(v, Qsh[2][d], a2);
            a3 = fmaf(v, Qsh[3][d], a3);
        }
        Qt_g[(size_t)(base + 0) * QTROW + t] = f2bf(a0);
        Qt_g[(size_t)(base + 1) * QTROW + t] = f2bf(a1);
        Qt_g[(size_t)(base + 2) * QTROW + t] = f2bf(a2);
        Qt_g[(size_t)(base + 3) * QTROW + t] = f2bf(a3);
        float b0 = 0, b1 = 0, b2 = 0, b3 = 0;
#pragma unroll 8
        for (int d = 32; d < 64; ++d) {
            float v = tk[d * TSPAN1];
            b0 = fmaf(v, Qsh[0][d], b0);
            b1 = fmaf(v, Qsh[1][d], b1);
            b2 = fmaf(v, Qsh[2][d], b2);
            b3 = fmaf(v, Qsh[3][d], b3);
        }
        Qt_g[(size_t)(base + 0) * QTROW + TSPAN1 + t] = f2bf(b0);
        Qt_g[(size_t)(base + 1) * QTROW + TSPAN1 + t] = f2bf(b1);
        Qt_g[(size_t)(base + 2) * QTROW + TSPAN1 + t] = f2bf(b2);
        Qt_g[(size_t)(base + 3) * QTROW + TSPAN1 + t] = f2bf(b3);
    }
}

// grid=11: m<10 -> transpose 64x64 weights; m==10 -> tK_emb^T [64][366]
__global__ void transpose_kernel(const float* __restrict__ Wq,
                                 const float* __restrict__ Wk,
                                 const float* __restrict__ Wv,
                                 const float* __restrict__ W1,
                                 const float* __restrict__ W2,
                                 const float* __restrict__ tK_emb,
                                 float* __restrict__ wt,
                                 float* __restrict__ tKT) {
    int m = blockIdx.x;
    if (m < 10) {
        const float* src;
        switch (m % 5) {
            case 0: src = Wq; break;
            case 1: src = Wk; break;
            case 2: src = Wv; break;
            case 3: src = W1; break;
            default: src = W2; break;
        }
        src += (m / 5) * DD * DD;
        float* dst = wt + m * DD * DD;
        for (int e = threadIdx.x; e < DD * DD; e += 256) {
            int d = e >> 6, j = e & 63;
            dst[j * DD + d] = src[e];
        }
    } else {
        for (int e = threadIdx.x; e < TSPAN1 * DD; e += 256) {
            int t = e >> 6, d = e & 63;
            tKT[d * TSPAN1 + t] = tK_emb[e];
        }
    }
}

// Layer-0 entry + fused qt: 4 rows/block, wave per row. Embedding fused.
__global__ void ln_qkv_kernel(const int* __restrict__ log_ids,
                              const float* __restrict__ item_emb,
                              const float* __restrict__ g,
                              const float* __restrict__ bln,
                              const float* __restrict__ WqT, const float* __restrict__ bq,
                              const float* __restrict__ WkT, const float* __restrict__ bk,
                              const float* __restrict__ WvT, const float* __restrict__ bv,
                              const float* __restrict__ posK,
                              const float* __restrict__ posV,
                              const float* __restrict__ tKT,
                              float* __restrict__ q,
                              float* __restrict__ Q, float* __restrict__ K,
                              float* __restrict__ V,
                              unsigned short* __restrict__ Qt_g) {
    __shared__ float qs[4][DD], xs[4][DD], Qsh[4][DD];
    int tid = threadIdx.x;
    int wid = tid >> 6, d = tid & 63;
    int row = blockIdx.x * 4 + wid;
    int l = row % LLEN;
    int id = log_ids[row];
    float xv = (id == 0) ? 0.0f : item_emb[(size_t)id * DD + d] * 8.0f;  // sqrt(64)*keep
    xs[wid][d] = xv;
    float m = waveSum(xv) * (1.0f / 64.0f);
    float c = xv - m;
    float var = waveSum(c * c) * (1.0f / 64.0f);
    float qv = (c / sqrtf(var + 1e-8f)) * g[d] + bln[d];
    qs[wid][d] = qv;
    q[(size_t)row * DD + d] = qv;
    float aq = bq[d], ak = bk[d], av = bv[d];
#pragma unroll 8
    for (int j = 0; j < DD; ++j) {
        aq = fmaf(qs[wid][j], WqT[j * DD + d], aq);
        ak = fmaf(xs[wid][j], WkT[j * DD + d], ak);
        av = fmaf(xs[wid][j], WvT[j * DD + d], av);
    }
    Q[(size_t)row * DD + d] = aq;
    K[(size_t)row * DD + d] = ak + posK[l * DD + d];
    V[(size_t)row * DD + d] = av + posV[l * DD + d];
    Qsh[wid][d] = aq;
    __syncthreads();
    qt_tail(Qsh, tKT, Qt_g, blockIdx.x * 4);
}

// Attention (R9 structure; qt in bf16). wave-per-query {i,99-i,100+i,199-i};
// per-wave phases; qt_s staged (bf16, uint2 loads); 4-key score groups.
__global__ void attn_kernel(const float* __restrict__ Q,
                            const float* __restrict__ Keff,
                            const float* __restrict__ Veff,
                            const int* __restrict__ log_times,
                            const unsigned short* __restrict__ Qt_g,
                            const float* __restrict__ tV_emb,
                            float* __restrict__ out) {
    __shared__ int t_s[LLEN];
    __shared__ float sc[4][HH][LLEN];
    __shared__ unsigned short tm_s[4][LLEN];
    __shared__ __align__(8) unsigned short qt_s[4][QTROW];

    int tid = threadIdx.x;
    int wid = tid >> 6;
    int lane = tid & 63;
    int bi = blockIdx.x / 50;
    int i = blockIdx.x % 50;
    int qi = (wid == 0) ? i : (wid == 1) ? (99 - i) : (wid == 2) ? (100 + i) : (199 - i);
    int row = bi * LLEN + qi;
    int len = qi + 1;

    if (tid < LLEN) t_s[tid] = log_times[bi * LLEN + tid];
    __syncthreads();

    // stage this query's Qt row (732 bf16 = 183 uint2) into LDS
    {
        const uint2* qtrow2 = (const uint2*)(Qt_g + (size_t)row * QTROW);
        uint2* qts2 = (uint2*)&qt_s[wid][0];
        for (int e = lane; e < 183; e += 64) qts2[e] = qtrow2[e];
    }

    // bucket table for this query
    int tq = t_s[qi];
    for (int k = lane; k < len; k += 64) {
        int dt = tq - t_s[k];
        if (dt < 0) dt = -dt;
        float dtf = fminf((float)dt * (1.0f / 86400.0f), 365.0f);
        tm_s[wid][k] = (unsigned short)(int)dtf;
    }

    int h = lane >> 5;       // head
    int l5 = lane & 31;
    int cch = l5 >> 2;       // channel chunk 0..7
    int jo = l5 & 3;         // key offset in group
    float4 qv = ((const float4*)(Q + (size_t)row * DD))[h * 8 + cch];
    const float4* K4 = (const float4*)(Keff + (size_t)bi * LLEN * DD);
    const float scale = 0.17677669529663687f;  // 1/sqrt(32)

    // phase 1: scores, 4 keys per iteration
    for (int k0 = 0; k0 < len; k0 += 4) {
        int k = k0 + jo;
        int kc = (k < len) ? k : (len - 1);
        int bucket = tm_s[wid][kc];
        float4 kv = K4[kc * 16 + h * 8 + cch];
        float p = qv.x * kv.x + qv.y * kv.y + qv.z * kv.z + qv.w * kv.w;
        p += __shfl_xor(p, 4);
        p += __shfl_xor(p, 8);
        p += __shfl_xor(p, 16);   // full 32-dot for (h, key k)
        float s = (p + bf2f(qt_s[wid][h * TSPAN1 + bucket])) * scale;
        if (cch == 0 && k < len) sc[wid][h][k] = s;
    }

    // phase 2: softmax (lanes 0..31 head 0, 32..63 head 1; same wave)
    {
        float m = -INFINITY;
        for (int k = l5; k < len; k += 32) m = fmaxf(m, sc[wid][h][k]);
        m = halfMax(m);
        float s = 0.0f;
        for (int k = l5; k < len; k += 32) {
            float e = expf(sc[wid][h][k] - m);
            sc[wid][h][k] = e;
            s += e;
        }
        s = halfSum(s);
        float inv = 1.0f / s;
        for (int k = l5; k < len; k += 32) sc[wid][h][k] *= inv;
    }

    // phase 3: out[d] = sum_k A[h][k] * (V_eff[k][d] + tV[bucket[k]][d])
    const float* Vb = Veff + (size_t)bi * LLEN * DD + lane;
    const float* tVl = tV_emb + lane;
    float acc0 = 0.0f, acc1 = 0.0f, acc2 = 0.0f, acc3 = 0.0f;
    int k = 0;
    for (; k + 4 <= len; k += 4) {
        int b0 = tm_s[wid][k + 0];
        int b1 = tm_s[wid][k + 1];
        int b2 = tm_s[wid][k + 2];
        int b3 = tm_s[wid][k + 3];
        float a0 = sc[wid][h][k + 0];
        float a1 = sc[wid][h][k + 1];
        float a2 = sc[wid][h][k + 2];
        float a3 = sc[wid][h][k + 3];
        acc0 = fmaf(a0, Vb[(k + 0) * DD] + tVl[b0 * DD], acc0);
        acc1 = fmaf(a1, Vb[(k + 1) * DD] + tVl[b1 * DD], acc1);
        acc2 = fmaf(a2, Vb[(k + 2) * DD] + tVl[b2 * DD], acc2);
        acc3 = fmaf(a3, Vb[(k + 3) * DD] + tVl[b3 * DD], acc3);
    }
    for (; k < len; ++k) {
        int b0 = tm_s[wid][k];
        acc0 = fmaf(sc[wid][h][k], Vb[k * DD] + tVl[b0 * DD], acc0);
    }
    out[(size_t)row * DD + lane] = (acc0 + acc1) + (acc2 + acc3);
}

// MID + fused qt: addln_ffn(layer i) + ln_qkv(layer i+1) + qt tail.
__global__ void mid_kernel(const float* __restrict__ qin,
                           const float* __restrict__ att,
                           const float* __restrict__ g2, const float* __restrict__ b2ln,
                           const float* __restrict__ W1T, const float* __restrict__ b1v,
                           const float* __restrict__ W2T, const float* __restrict__ b2v,
                           const int* __restrict__ log_ids,
                           const float* __restrict__ g1n, const float* __restrict__ b1n,
                           const float* __restrict__ WqT, const float* __restrict__ bq,
                           const float* __restrict__ WkT, const float* __restrict__ bk,
                           const float* __restrict__ WvT, const float* __restrict__ bv,
                           const float* __restrict__ posK,
                           const float* __restrict__ posV,
                           const float* __restrict__ tKT,
                           float* __restrict__ q,
                           float* __restrict__ Q, float* __restrict__ K,
                           float* __restrict__ V,
                           unsigned short* __restrict__ Qt_g) {
    __shared__ float xs[4][DD], hs[4][DD], qs[4][DD], Qsh[4][DD];
    int tid = threadIdx.x;
    int wid = tid >> 6, d = tid & 63;
    int row = blockIdx.x * 4 + wid;
    int l = row % LLEN;
    // --- addln + FFN ---
    float v = qin[(size_t)row * DD + d] + att[(size_t)row * DD + d];
    float m = waveSum(v) * (1.0f / 64.0f);
    float c = v - m;
    float var = waveSum(c * c) * (1.0f / 64.0f);
    float xv = (c / sqrtf(var + 1e-8f)) * g2[d] + b2ln[d];
    xs[wid][d] = xv;
    float a = b1v[d];
#pragma unroll 8
    for (int j = 0; j < DD; ++j) a = fmaf(xs[wid][j], W1T[j * DD + d], a);
    hs[wid][d] = fmaxf(a, 0.0f);
    float o = b2v[d];
#pragma unroll 8
    for (int j = 0; j < DD; ++j) o = fmaf(hs[wid][j], W2T[j * DD + d], o);
    float res = xv + o;
    if (log_ids[row] == 0) res = 0.0f;
    // --- next layer: LN1 + QKV projection ---
    float m2 = waveSum(res) * (1.0f / 64.0f);
    float c2 = res - m2;
    float var2 = waveSum(c2 * c2) * (1.0f / 64.0f);
    float qv = (c2 / sqrtf(var2 + 1e-8f)) * g1n[d] + b1n[d];
    qs[wid][d] = qv;
    xs[wid][d] = res;
    q[(size_t)row * DD + d] = qv;
    float aq = bq[d], ak = bk[d], av = bv[d];
#pragma unroll 8
    for (int j = 0; j < DD; ++j) {
        aq = fmaf(qs[wid][j], WqT[j * DD + d], aq);
        ak = fmaf(xs[wid][j], WkT[j * DD + d], ak);
        av = fmaf(xs[wid][j], WvT[j * DD + d], av);
    }
    Q[(size_t)row * DD + d] = aq;
    K[(size_t)row * DD + d] = ak + posK[l * DD + d];
    V[(size_t)row * DD + d] = av + posV[l * DD + d];
    Qsh[wid][d] = aq;
    __syncthreads();
    qt_tail(Qsh, tKT, Qt_g, blockIdx.x * 4);
}

// END: addln_ffn(last layer) fused with final LN + logits. 4 rows/block.
__global__ void end_kernel(const float* __restrict__ qin,
                           const float* __restrict__ att,
                           const float* __restrict__ g2, const float* __restrict__ b2ln,
                           const float* __restrict__ W1T, const float* __restrict__ b1v,
                           const float* __restrict__ W2T, const float* __restrict__ b2v,
                           const int* __restrict__ log_ids,
                           const float* __restrict__ lnf_g, const float* __restrict__ lnf_b,
                           const float* __restrict__ item_emb,
                           const int* __restrict__ pos_ids,
                           const int* __restrict__ neg_ids,
                           float* __restrict__ out) {
    __shared__ float xs[4][DD], hs[4][DD];
    int tid = threadIdx.x;
    int wid = tid >> 6, d = tid & 63;
    int row = blockIdx.x * 4 + wid;
    float v = qin[(size_t)row * DD + d] + att[(size_t)row * DD + d];
    float m = waveSum(v) * (1.0f / 64.0f);
    float c = v - m;
    float var = waveSum(c * c) * (1.0f / 64.0f);
    float xv = (c / sqrtf(var + 1e-8f)) * g2[d] + b2ln[d];
    xs[wid][d] = xv;
    float a = b1v[d];
#pragma unroll 8
    for (int j = 0; j < DD; ++j) a = fmaf(xs[wid][j], W1T[j * DD + d], a);
    hs[wid][d] = fmaxf(a, 0.0f);
    float o = b2v[d];
#pragma unroll 8
    for (int j = 0; j < DD; ++j) o = fmaf(hs[wid][j], W2T[j * DD + d], o);
    float res = xv + o;
    if (log_ids[row] == 0) res = 0.0f;
    // --- final LN + logits ---
    float m2 = waveSum(res) * (1.0f / 64.0f);
    float c2 = res - m2;
    float var2 = waveSum(c2 * c2) * (1.0f / 64.0f);
    float f = (c2 / sqrtf(var2 + 1e-8f)) * lnf_g[d] + lnf_b[d];
    int pid = pos_ids[row];
    int nid = neg_ids[row];
    float p = waveSum(f * item_emb[(size_t)pid * DD + d]);
    float n = waveSum(f * item_emb[(size_t)nid * DD + d]);
    if (d == 0) {
        out[row] = p;
        out[BB * LLEN + row] = n;
    }
}

extern "C" void kernel_launch(void* const* d_in, const int* in_sizes, int n_in,
                              void* d_out, int out_size, void* d_ws, size_t ws_size,
                              hipStream_t stream) {
    const int* log_ids = (const int*)d_in[0];
    const int* log_times = (const int*)d_in[1];
    const int* pos_ids = (const int*)d_in[2];
    const int* neg_ids = (const int*)d_in[3];
    const float* item_emb = (const float*)d_in[4];
    const float* posK = (const float*)d_in[5];
    const float* posV = (const float*)d_in[6];
    const float* tK_emb = (const float*)d_in[7];
    const float* tV_emb = (const float*)d_in[8];
    const float* ln1_g = (const float*)d_in[9];
    const float* ln1_b = (const float*)d_in[10];
    const float* Wq = (const float*)d_in[11];
    const float* bq = (const float*)d_in[12];
    const float* Wk = (const float*)d_in[13];
    const float* bk = (const float*)d_in[14];
    const float* Wv = (const float*)d_in[15];
    const float* bv = (const float*)d_in[16];
    const float* ln2_g = (const float*)d_in[17];
    const float* ln2_b = (const float*)d_in[18];
    const float* W1 = (const float*)d_in[19];
    const float* b1 = (const float*)d_in[20];
    const float* W2 = (const float*)d_in[21];
    const float* b2 = (const float*)d_in[22];
    const float* lnf_g = (const float*)d_in[23];
    const float* lnf_b = (const float*)d_in[24];

    float* ws = (float*)d_ws;
    float* q = ws;                        // ln1 output (residual)
    float* Qb = q + BLD;
    float* Kb = Qb + BLD;
    float* Vb = Kb + BLD;
    float* att = Vb + BLD;
    float* wt = att + BLD;                // 10 x 64x64 transposed weights
    float* tKT = wt + 10 * DD * DD;       // [64][366]
    unsigned short* Qt = (unsigned short*)(tKT + DD * TSPAN1);  // [6400][732] bf16

    const int nrow = BB * LLEN;           // 6400

    const float* W1T0 = wt + 3 * DD * DD;
    const float* W2T0 = wt + 4 * DD * DD;
    const float* W1T1 = wt + 8 * DD * DD;
    const float* W2T1 = wt + 9 * DD * DD;

    transpose_kernel<<<11, 256, 0, stream>>>(Wq, Wk, Wv, W1, W2, tK_emb, wt, tKT);

    // layer 0 entry (embed + qt fused)
    ln_qkv_kernel<<<nrow / 4, 256, 0, stream>>>(log_ids, item_emb,
                                                ln1_g, ln1_b,
                                                wt + 0 * DD * DD, bq,
                                                wt + 1 * DD * DD, bk,
                                                wt + 2 * DD * DD, bv,
                                                posK, posV, tKT,
                                                q, Qb, Kb, Vb, Qt);
    attn_kernel<<<BB * 50, 256, 0, stream>>>(Qb, Kb, Vb, log_times, Qt, tV_emb, att);

    // layer 0 tail + layer 1 entry (+ qt fused)
    mid_kernel<<<nrow / 4, 256, 0, stream>>>(q, att,
                                             ln2_g, ln2_b,
                                             W1T0, b1, W2T0, b2,
                                             log_ids,
                                             ln1_g + DD, ln1_b + DD,
                                             wt + 5 * DD * DD, bq + DD,
                                             wt + 6 * DD * DD, bk + DD,
                                             wt + 7 * DD * DD, bv + DD,
                                             posK, posV, tKT,
                                             q, Qb, Kb, Vb, Qt);
    attn_kernel<<<BB * 50, 256, 0, stream>>>(Qb, Kb, Vb, log_times, Qt, tV_emb, att);

    // layer 1 tail + final logits
    end_kernel<<<nrow / 4, 256, 0, stream>>>(q, att,
                                             ln2_g + DD, ln2_b + DD,
                                             W1T1, b1 + DD, W2T1, b2 + DD,
                                             log_ids,
                                             lnf_g, lnf_b, item_emb,
                                             pos_ids, neg_ids, (float*)d_out);
}

// Round 21
// 179.653 us; speedup vs baseline: 1.0334x; 1.0002x over previous
//
#include <hip/hip_runtime.h>
#include <math.h>

// TiSASRec forward on MI355X — round 20 (= R18 resubmitted; 2x infra failure):
//  - Base: R15/R17 (179.4-179.7us; attn 45.0-45.3us).
//  - DS-pipe arithmetic (700 DS wave-instrs/wave x 25 waves/CU x 5.8cy = 42us)
//    matches attn's measured 45us => LDS-throughput bound. Single change:
//    phase-3's 8 scalar broadcast LDS reads per 4 keys -> 2 ds_read_b128 of
//    packed float2{A,bucketf}. V/tV loads, lane mapping, output: R15-exact.
// B=32, L=200, D=64, H=2, dh=32, NL=2.
#define BB 32
#define LLEN 200
#define DD 64
#define HH 2
#define NLAYER 2
#define BLD (BB * LLEN * DD)
#define TSPAN1 366   // TIME_SPAN+1
#define QTROW (2 * TSPAN1)   // 732 bf16 per row

__device__ inline float waveSum(float v) {
#pragma unroll
    for (int off = 32; off > 0; off >>= 1) v += __shfl_xor(v, off);
    return v;
}
__device__ inline float halfSum(float v) {
    v += __shfl_xor(v, 1);
    v += __shfl_xor(v, 2);
    v += __shfl_xor(v, 4);
    v += __shfl_xor(v, 8);
    v += __shfl_xor(v, 16);
    return v;
}
__device__ inline float halfMax(float v) {
    v = fmaxf(v, __shfl_xor(v, 1));
    v = fmaxf(v, __shfl_xor(v, 2));
    v = fmaxf(v, __shfl_xor(v, 4));
    v = fmaxf(v, __shfl_xor(v, 8));
    v = fmaxf(v, __shfl_xor(v, 16));
    return v;
}

// f32 -> bf16 with round-to-nearest-even
__device__ inline unsigned short f2bf(float f) {
    unsigned u = __float_as_uint(f);
    u = (u + 0x7FFFu + ((u >> 16) & 1u)) >> 16;
    return (unsigned short)u;
}
__device__ inline float bf2f(unsigned short b) {
    return __uint_as_float(((unsigned)b) << 16);
}

// qt tail (R9 structure): thread t owns bucket t (coalesced tKT column
// reads); Qt[row][h*366+t] = Qsh[r] . tK[t] (head h), stored bf16.
__device__ inline void qt_tail(const float (*Qsh)[DD], const float* __restrict__ tKT,
                               unsigned short* __restrict__ Qt_g, int base) {
    int tid = threadIdx.x;
    for (int t = tid; t < TSPAN1; t += 256) {
        const float* tk = tKT + t;
        float a0 = 0, a1 = 0, a2 = 0, a3 = 0;
#pragma unroll 8
        for (int d = 0; d < 32; ++d) {
            float v = tk[d * TSPAN1];
            a0 = fmaf(v, Qsh[0][d], a0);
            a1 = fmaf(v, Qsh[1][d], a1);
            a2 = fmaf(v, Qsh[2][d], a2);
            a3 = fmaf(v, Qsh[3][d], a3);
        }
        Qt_g[(size_t)(base + 0) * QTROW + t] = f2bf(a0);
        Qt_g[(size_t)(base + 1) * QTROW + t] = f2bf(a1);
        Qt_g[(size_t)(base + 2) * QTROW + t] = f2bf(a2);
        Qt_g[(size_t)(base + 3) * QTROW + t] = f2bf(a3);
        float b0 = 0, b1 = 0, b2 = 0, b3 = 0;
#pragma unroll 8
        for (int d = 32; d < 64; ++d) {
            float v = tk[d * TSPAN1];
            b0 = fmaf(v, Qsh[0][d], b0);
            b1 = fmaf(v, Qsh[1][d], b1);
            b2 = fmaf(v, Qsh[2][d], b2);
            b3 = fmaf(v, Qsh[3][d], b3);
        }
        Qt_g[(size_t)(base + 0) * QTROW + TSPAN1 + t] = f2bf(b0);
        Qt_g[(size_t)(base + 1) * QTROW + TSPAN1 + t] = f2bf(b1);
        Qt_g[(size_t)(base + 2) * QTROW + TSPAN1 + t] = f2bf(b2);
        Qt_g[(size_t)(base + 3) * QTROW + TSPAN1 + t] = f2bf(b3);
    }
}

// grid=11: m<10 -> transpose 64x64 weights; m==10 -> tK_emb^T [64][366]
__global__ void transpose_kernel(const float* __restrict__ Wq,
                                 const float* __restrict__ Wk,
                                 const float* __restrict__ Wv,
                                 const float* __restrict__ W1,
                                 const float* __restrict__ W2,
                                 const float* __restrict__ tK_emb,
                                 float* __restrict__ wt,
                                 float* __restrict__ tKT) {
    int m = blockIdx.x;
    if (m < 10) {
        const float* src;
        switch (m % 5) {
            case 0: src = Wq; break;
            case 1: src = Wk; break;
            case 2: src = Wv; break;
            case 3: src = W1; break;
            default: src = W2; break;
        }
        src += (m / 5) * DD * DD;
        float* dst = wt + m * DD * DD;
        for (int e = threadIdx.x; e < DD * DD; e += 256) {
            int d = e >> 6, j = e & 63;
            dst[j * DD + d] = src[e];
        }
    } else {
        for (int e = threadIdx.x; e < TSPAN1 * DD; e += 256) {
            int t = e >> 6, d = e & 63;
            tKT[d * TSPAN1 + t] = tK_emb[e];
        }
    }
}

// Layer-0 entry + fused qt: 4 rows/block, wave per row. Embedding fused.
__global__ void ln_qkv_kernel(const int* __restrict__ log_ids,
                              const float* __restrict__ item_emb,
                              const float* __restrict__ g,
                              const float* __restrict__ bln,
                              const float* __restrict__ WqT, const float* __restrict__ bq,
                              const float* __restrict__ WkT, const float* __restrict__ bk,
                              const float* __restrict__ WvT, const float* __restrict__ bv,
                              const float* __restrict__ posK,
                              const float* __restrict__ posV,
                              const float* __restrict__ tKT,
                              float* __restrict__ q,
                              float* __restrict__ Q, float* __restrict__ K,
                              float* __restrict__ V,
                              unsigned short* __restrict__ Qt_g) {
    __shared__ float qs[4][DD], xs[4][DD], Qsh[4][DD];
    int tid = threadIdx.x;
    int wid = tid >> 6, d = tid & 63;
    int row = blockIdx.x * 4 + wid;
    int l = row % LLEN;
    int id = log_ids[row];
    float xv = (id == 0) ? 0.0f : item_emb[(size_t)id * DD + d] * 8.0f;  // sqrt(64)*keep
    xs[wid][d] = xv;
    float m = waveSum(xv) * (1.0f / 64.0f);
    float c = xv - m;
    float var = waveSum(c * c) * (1.0f / 64.0f);
    float qv = (c / sqrtf(var + 1e-8f)) * g[d] + bln[d];
    qs[wid][d] = qv;
    q[(size_t)row * DD + d] = qv;
    float aq = bq[d], ak = bk[d], av = bv[d];
#pragma unroll 8
    for (int j = 0; j < DD; ++j) {
        aq = fmaf(qs[wid][j], WqT[j * DD + d], aq);
        ak = fmaf(xs[wid][j], WkT[j * DD + d], ak);
        av = fmaf(xs[wid][j], WvT[j * DD + d], av);
    }
    Q[(size_t)row * DD + d] = aq;
    K[(size_t)row * DD + d] = ak + posK[l * DD + d];
    V[(size_t)row * DD + d] = av + posV[l * DD + d];
    Qsh[wid][d] = aq;
    __syncthreads();
    qt_tail(Qsh, tKT, Qt_g, blockIdx.x * 4);
}

// Attention: R15 structure with packed {A,bucketf} LDS for phase 3.
__global__ void attn_kernel(const float* __restrict__ Q,
                            const float* __restrict__ Keff,
                            const float* __restrict__ Veff,
                            const int* __restrict__ log_times,
                            const unsigned short* __restrict__ Qt_g,
                            const float* __restrict__ tV_emb,
                            float* __restrict__ out) {
    __shared__ int t_s[LLEN];
    __shared__ __align__(16) float2 scp[4][HH][LLEN];   // {A, bucketf}
    __shared__ unsigned short tm_s[4][LLEN];
    __shared__ __align__(8) unsigned short qt_s[4][QTROW];

    int tid = threadIdx.x;
    int wid = tid >> 6;
    int lane = tid & 63;
    int bi = blockIdx.x / 50;
    int i = blockIdx.x % 50;
    int qi = (wid == 0) ? i : (wid == 1) ? (99 - i) : (wid == 2) ? (100 + i) : (199 - i);
    int row = bi * LLEN + qi;
    int len = qi + 1;

    if (tid < LLEN) t_s[tid] = log_times[bi * LLEN + tid];
    __syncthreads();

    // stage this query's Qt row (732 bf16 = 183 uint2) into LDS
    {
        const uint2* qtrow2 = (const uint2*)(Qt_g + (size_t)row * QTROW);
        uint2* qts2 = (uint2*)&qt_s[wid][0];
        for (int e = lane; e < 183; e += 64) qts2[e] = qtrow2[e];
    }

    // bucket table: ushort for phase-1 lookup + float copy in packed scp
    int tq = t_s[qi];
    for (int k = lane; k < len; k += 64) {
        int dt = tq - t_s[k];
        if (dt < 0) dt = -dt;
        float dtf = fminf((float)dt * (1.0f / 86400.0f), 365.0f);
        int bk = (int)dtf;
        tm_s[wid][k] = (unsigned short)bk;
        float bf = (float)bk;
        scp[wid][0][k].y = bf;
        scp[wid][1][k].y = bf;
    }

    int h = lane >> 5;       // head
    int l5 = lane & 31;
    int cch = l5 >> 2;       // channel chunk 0..7
    int jo = l5 & 3;         // key offset in group
    float4 qv = ((const float4*)(Q + (size_t)row * DD))[h * 8 + cch];
    const float4* K4 = (const float4*)(Keff + (size_t)bi * LLEN * DD);
    const float scale = 0.17677669529663687f;  // 1/sqrt(32)

    // phase 1: scores, 4 keys per iteration
    for (int k0 = 0; k0 < len; k0 += 4) {
        int k = k0 + jo;
        int kc = (k < len) ? k : (len - 1);
        int bucket = tm_s[wid][kc];
        float4 kv = K4[kc * 16 + h * 8 + cch];
        float p = qv.x * kv.x + qv.y * kv.y + qv.z * kv.z + qv.w * kv.w;
        p += __shfl_xor(p, 4);
        p += __shfl_xor(p, 8);
        p += __shfl_xor(p, 16);   // full 32-dot for (h, key k)
        float s = (p + bf2f(qt_s[wid][h * TSPAN1 + bucket])) * scale;
        if (cch == 0 && k < len) scp[wid][h][k].x = s;
    }

    // phase 2: softmax on scp[.x] (lanes 0..31 head 0, 32..63 head 1)
    {
        float m = -INFINITY;
        for (int k = l5; k < len; k += 32) m = fmaxf(m, scp[wid][h][k].x);
        m = halfMax(m);
        float s = 0.0f;
        for (int k = l5; k < len; k += 32) {
            float e = expf(scp[wid][h][k].x - m);
            scp[wid][h][k].x = e;
            s += e;
        }
        s = halfSum(s);
        float inv = 1.0f / s;
        for (int k = l5; k < len; k += 32) scp[wid][h][k].x *= inv;
    }

    // phase 3: out[d] = sum_k A[k]*(V[k][d] + tV[bucket[k]][d]).
    // A+bucket fetched 2 keys per ds_read_b128 (2 DS/4 keys vs 8 before);
    // V/tV loads and lane=channel mapping R15-exact.
    const float* Vb = Veff + (size_t)bi * LLEN * DD + lane;
    const float* tVl = tV_emb + lane;
    float acc0 = 0.0f, acc1 = 0.0f, acc2 = 0.0f, acc3 = 0.0f;
    int k = 0;
    for (; k + 4 <= len; k += 4) {
        float4 p01 = *(const float4*)&scp[wid][h][k];       // {A0,b0f,A1,b1f}
        float4 p23 = *(const float4*)&scp[wid][h][k + 2];   // {A2,b2f,A3,b3f}
        acc0 = fmaf(p01.x, Vb[(k + 0) * DD] + tVl[(int)p01.y * DD], acc0);
        acc1 = fmaf(p01.z, Vb[(k + 1) * DD] + tVl[(int)p01.w * DD], acc1);
        acc2 = fmaf(p23.x, Vb[(k + 2) * DD] + tVl[(int)p23.y * DD], acc2);
        acc3 = fmaf(p23.z, Vb[(k + 3) * DD] + tVl[(int)p23.w * DD], acc3);
    }
    for (; k < len; ++k) {
        float2 p = scp[wid][h][k];
        acc0 = fmaf(p.x, Vb[k * DD] + tVl[(int)p.y * DD], acc0);
    }
    out[(size_t)row * DD + lane] = (acc0 + acc1) + (acc2 + acc3);
}

// MID + fused qt: addln_ffn(layer i) + ln_qkv(layer i+1) + qt tail.
__global__ void mid_kernel(const float* __restrict__ qin,
                           const float* __restrict__ att,
                           const float* __restrict__ g2, const float* __restrict__ b2ln,
                           const float* __restrict__ W1T, const float* __restrict__ b1v,
                           const float* __restrict__ W2T, const float* __restrict__ b2v,
                           const int* __restrict__ log_ids,
                           const float* __restrict__ g1n, const float* __restrict__ b1n,
                           const float* __restrict__ WqT, const float* __restrict__ bq,
                           const float* __restrict__ WkT, const float* __restrict__ bk,
                           const float* __restrict__ WvT, const float* __restrict__ bv,
                           const float* __restrict__ posK,
                           const float* __restrict__ posV,
                           const float* __restrict__ tKT,
                           float* __restrict__ q,
                           float* __restrict__ Q, float* __restrict__ K,
                           float* __restrict__ V,
                           unsigned short* __restrict__ Qt_g) {
    __shared__ float xs[4][DD], hs[4][DD], qs[4][DD], Qsh[4][DD];
    int tid = threadIdx.x;
    int wid = tid >> 6, d = tid & 63;
    int row = blockIdx.x * 4 + wid;
    int l = row % LLEN;
    // --- addln + FFN ---
    float v = qin[(size_t)row * DD + d] + att[(size_t)row * DD + d];
    float m = waveSum(v) * (1.0f / 64.0f);
    float c = v - m;
    float var = waveSum(c * c) * (1.0f / 64.0f);
    float xv = (c / sqrtf(var + 1e-8f)) * g2[d] + b2ln[d];
    xs[wid][d] = xv;
    float a = b1v[d];
#pragma unroll 8
    for (int j = 0; j < DD; ++j) a = fmaf(xs[wid][j], W1T[j * DD + d], a);
    hs[wid][d] = fmaxf(a, 0.0f);
    float o = b2v[d];
#pragma unroll 8
    for (int j = 0; j < DD; ++j) o = fmaf(hs[wid][j], W2T[j * DD + d], o);
    float res = xv + o;
    if (log_ids[row] == 0) res = 0.0f;
    // --- next layer: LN1 + QKV projection ---
    float m2 = waveSum(res) * (1.0f / 64.0f);
    float c2 = res - m2;
    float var2 = waveSum(c2 * c2) * (1.0f / 64.0f);
    float qv = (c2 / sqrtf(var2 + 1e-8f)) * g1n[d] + b1n[d];
    qs[wid][d] = qv;
    xs[wid][d] = res;
    q[(size_t)row * DD + d] = qv;
    float aq = bq[d], ak = bk[d], av = bv[d];
#pragma unroll 8
    for (int j = 0; j < DD; ++j) {
        aq = fmaf(qs[wid][j], WqT[j * DD + d], aq);
        ak = fmaf(xs[wid][j], WkT[j * DD + d], ak);
        av = fmaf(xs[wid][j], WvT[j * DD + d], av);
    }
    Q[(size_t)row * DD + d] = aq;
    K[(size_t)row * DD + d] = ak + posK[l * DD + d];
    V[(size_t)row * DD + d] = av + posV[l * DD + d];
    Qsh[wid][d] = aq;
    __syncthreads();
    qt_tail(Qsh, tKT, Qt_g, blockIdx.x * 4);
}

// END: addln_ffn(last layer) fused with final LN + logits. 4 rows/block.
__global__ void end_kernel(const float* __restrict__ qin,
                           const float* __restrict__ att,
                           const float* __restrict__ g2, const float* __restrict__ b2ln,
                           const float* __restrict__ W1T, const float* __restrict__ b1v,
                           const float* __restrict__ W2T, const float* __restrict__ b2v,
                           const int* __restrict__ log_ids,
                           const float* __restrict__ lnf_g, const float* __restrict__ lnf_b,
                           const float* __restrict__ item_emb,
                           const int* __restrict__ pos_ids,
                           const int* __restrict__ neg_ids,
                           float* __restrict__ out) {
    __shared__ float xs[4][DD], hs[4][DD];
    int tid = threadIdx.x;
    int wid = tid >> 6, d = tid & 63;
    int row = blockIdx.x * 4 + wid;
    float v = qin[(size_t)row * DD + d] + att[(size_t)row * DD + d];
    float m = waveSum(v) * (1.0f / 64.0f);
    float c = v - m;
    float var = waveSum(c * c) * (1.0f / 64.0f);
    float xv = (c / sqrtf(var + 1e-8f)) * g2[d] + b2ln[d];
    xs[wid][d] = xv;
    float a = b1v[d];
#pragma unroll 8
    for (int j = 0; j < DD; ++j) a = fmaf(xs[wid][j], W1T[j * DD + d], a);
    hs[wid][d] = fmaxf(a, 0.0f);
    float o = b2v[d];
#pragma unroll 8
    for (int j = 0; j < DD; ++j) o = fmaf(hs[wid][j], W2T[j * DD + d], o);
    float res = xv + o;
    if (log_ids[row] == 0) res = 0.0f;
    // --- final LN + logits ---
    float m2 = waveSum(res) * (1.0f / 64.0f);
    float c2 = res - m2;
    float var2 = waveSum(c2 * c2) * (1.0f / 64.0f);
    float f = (c2 / sqrtf(var2 + 1e-8f)) * lnf_g[d] + lnf_b[d];
    int pid = pos_ids[row];
    int nid = neg_ids[row];
    float p = waveSum(f * item_emb[(size_t)pid * DD + d]);
    float n = waveSum(f * item_emb[(size_t)nid * DD + d]);
    if (d == 0) {
        out[row] = p;
        out[BB * LLEN + row] = n;
    }
}

extern "C" void kernel_launch(void* const* d_in, const int* in_sizes, int n_in,
                              void* d_out, int out_size, void* d_ws, size_t ws_size,
                              hipStream_t stream) {
    const int* log_ids = (const int*)d_in[0];
    const int* log_times = (const int*)d_in[1];
    const int* pos_ids = (const int*)d_in[2];
    const int* neg_ids = (const int*)d_in[3];
    const float* item_emb = (const float*)d_in[4];
    const float* posK = (const float*)d_in[5];
    const float* posV = (const float*)d_in[6];
    const float* tK_emb = (const float*)d_in[7];
    const float* tV_emb = (const float*)d_in[8];
    const float* ln1_g = (const float*)d_in[9];
    const float* ln1_b = (const float*)d_in[10];
    const float* Wq = (const float*)d_in[11];
    const float* bq = (const float*)d_in[12];
    const float* Wk = (const float*)d_in[13];
    const float* bk = (const float*)d_in[14];
    const float* Wv = (const float*)d_in[15];
    const float* bv = (const float*)d_in[16];
    const float* ln2_g = (const float*)d_in[17];
    const float* ln2_b = (const float*)d_in[18];
    const float* W1 = (const float*)d_in[19];
    const float* b1 = (const float*)d_in[20];
    const float* W2 = (const float*)d_in[21];
    const float* b2 = (const float*)d_in[22];
    const float* lnf_g = (const float*)d_in[23];
    const float* lnf_b = (const float*)d_in[24];

    float* ws = (float*)d_ws;
    float* q = ws;                        // ln1 output (residual)
    float* Qb = q + BLD;
    float* Kb = Qb + BLD;
    float* Vb = Kb + BLD;
    float* att = Vb + BLD;
    float* wt = att + BLD;                // 10 x 64x64 transposed weights
    float* tKT = wt + 10 * DD * DD;       // [64][366]
    unsigned short* Qt = (unsigned short*)(tKT + DD * TSPAN1);  // [6400][732] bf16

    const int nrow = BB * LLEN;           // 6400

    const float* W1T0 = wt + 3 * DD * DD;
    const float* W2T0 = wt + 4 * DD * DD;
    const float* W1T1 = wt + 8 * DD * DD;
    const float* W2T1 = wt + 9 * DD * DD;

    transpose_kernel<<<11, 256, 0, stream>>>(Wq, Wk, Wv, W1, W2, tK_emb, wt, tKT);

    // layer 0 entry (embed + qt fused)
    ln_qkv_kernel<<<nrow / 4, 256, 0, stream>>>(log_ids, item_emb,
                                                ln1_g, ln1_b,
                                                wt + 0 * DD * DD, bq,
                                                wt + 1 * DD * DD, bk,
                                                wt + 2 * DD * DD, bv,
                                                posK, posV, tKT,
                                                q, Qb, Kb, Vb, Qt);
    attn_kernel<<<BB * 50, 256, 0, stream>>>(Qb, Kb, Vb, log_times, Qt, tV_emb, att);

    // layer 0 tail + layer 1 entry (+ qt fused)
    mid_kernel<<<nrow / 4, 256, 0, stream>>>(q, att,
                                             ln2_g, ln2_b,
                                             W1T0, b1, W2T0, b2,
                                             log_ids,
                                             ln1_g + DD, ln1_b + DD,
                                             wt + 5 * DD * DD, bq + DD,
                                             wt + 6 * DD * DD, bk + DD,
                                             wt + 7 * DD * DD, bv + DD,
                                             posK, posV, tKT,
                                             q, Qb, Kb, Vb, Qt);
    attn_kernel<<<BB * 50, 256, 0, stream>>>(Qb, Kb, Vb, log_times, Qt, tV_emb, att);

    // layer 1 tail + final logits
    end_kernel<<<nrow / 4, 256, 0, stream>>>(q, att,
                                             ln2_g + DD, ln2_b + DD,
                                             W1T1, b1 + DD, W2T1, b2 + DD,
                                             log_ids,
                                             lnf_g, lnf_b, item_emb,
                                             pos_ids, neg_ids, (float*)d_out);
}

// Round 23
// 179.507 us; speedup vs baseline: 1.0342x; 1.0008x over previous
//
#include <hip/hip_runtime.h>
#include <math.h>

// TiSASRec forward on MI355X — round 22: FINAL = R15 byte-exact (measured
// best: 179.37us in R15; reproduced 179.69us in R17). R21 submission of this
// same code hit an infra failure; resubmitting unchanged.
//  - Config: R9 structure (fused producers, 5 launches) + bf16 Qt table.
//  - Session: 1027us (R2 baseline) -> 179.4us. Wins: coalesced wave-per-query
//    attn + Qt table, launch fusion, bf16 Qt. All further restructures
//    (7 attn variants, 2 megakernels, XCD remap, 2 DS diets) neutral/worse.
// B=32, L=200, D=64, H=2, dh=32, NL=2.
#define BB 32
#define LLEN 200
#define DD 64
#define HH 2
#define NLAYER 2
#define BLD (BB * LLEN * DD)
#define TSPAN1 366   // TIME_SPAN+1
#define QTROW (2 * TSPAN1)   // 732 bf16 per row

__device__ inline float waveSum(float v) {
#pragma unroll
    for (int off = 32; off > 0; off >>= 1) v += __shfl_xor(v, off);
    return v;
}
__device__ inline float halfSum(float v) {
    v += __shfl_xor(v, 1);
    v += __shfl_xor(v, 2);
    v += __shfl_xor(v, 4);
    v += __shfl_xor(v, 8);
    v += __shfl_xor(v, 16);
    return v;
}
__device__ inline float halfMax(float v) {
    v = fmaxf(v, __shfl_xor(v, 1));
    v = fmaxf(v, __shfl_xor(v, 2));
    v = fmaxf(v, __shfl_xor(v, 4));
    v = fmaxf(v, __shfl_xor(v, 8));
    v = fmaxf(v, __shfl_xor(v, 16));
    return v;
}

// f32 -> bf16 with round-to-nearest-even
__device__ inline unsigned short f2bf(float f) {
    unsigned u = __float_as_uint(f);
    u = (u + 0x7FFFu + ((u >> 16) & 1u)) >> 16;
    return (unsigned short)u;
}
__device__ inline float bf2f(unsigned short b) {
    return __uint_as_float(((unsigned)b) << 16);
}

// qt tail (R9 structure): thread t owns bucket t (coalesced tKT column
// reads); Qt[row][h*366+t] = Qsh[r] . tK[t] (head h), stored bf16.
__device__ inline void qt_tail(const float (*Qsh)[DD], const float* __restrict__ tKT,
                               unsigned short* __restrict__ Qt_g, int base) {
    int tid = threadIdx.x;
    for (int t = tid; t < TSPAN1; t += 256) {
        const float* tk = tKT + t;
        float a0 = 0, a1 = 0, a2 = 0, a3 = 0;
#pragma unroll 8
        for (int d = 0; d < 32; ++d) {
            float v = tk[d * TSPAN1];
            a0 = fmaf(v, Qsh[0][d], a0);
            a1 = fmaf(v, Qsh[1][d], a1);
            a2 = fmaf(v, Qsh[2][d], a2);
            a3 = fmaf(v, Qsh[3][d], a3);
        }
        Qt_g[(size_t)(base + 0) * QTROW + t] = f2bf(a0);
        Qt_g[(size_t)(base + 1) * QTROW + t] = f2bf(a1);
        Qt_g[(size_t)(base + 2) * QTROW + t] = f2bf(a2);
        Qt_g[(size_t)(base + 3) * QTROW + t] = f2bf(a3);
        float b0 = 0, b1 = 0, b2 = 0, b3 = 0;
#pragma unroll 8
        for (int d = 32; d < 64; ++d) {
            float v = tk[d * TSPAN1];
            b0 = fmaf(v, Qsh[0][d], b0);
            b1 = fmaf(v, Qsh[1][d], b1);
            b2 = fmaf(v, Qsh[2][d], b2);
            b3 = fmaf(v, Qsh[3][d], b3);
        }
        Qt_g[(size_t)(base + 0) * QTROW + TSPAN1 + t] = f2bf(b0);
        Qt_g[(size_t)(base + 1) * QTROW + TSPAN1 + t] = f2bf(b1);
        Qt_g[(size_t)(base + 2) * QTROW + TSPAN1 + t] = f2bf(b2);
        Qt_g[(size_t)(base + 3) * QTROW + TSPAN1 + t] = f2bf(b3);
    }
}

// grid=11: m<10 -> transpose 64x64 weights; m==10 -> tK_emb^T [64][366]
__global__ void transpose_kernel(const float* __restrict__ Wq,
                                 const float* __restrict__ Wk,
                                 const float* __restrict__ Wv,
                                 const float* __restrict__ W1,
                                 const float* __restrict__ W2,
                                 const float* __restrict__ tK_emb,
                                 float* __restrict__ wt,
                                 float* __restrict__ tKT) {
    int m = blockIdx.x;
    if (m < 10) {
        const float* src;
        switch (m % 5) {
            case 0: src = Wq; break;
            case 1: src = Wk; break;
            case 2: src = Wv; break;
            case 3: src = W1; break;
            default: src = W2; break;
        }
        src += (m / 5) * DD * DD;
        float* dst = wt + m * DD * DD;
        for (int e = threadIdx.x; e < DD * DD; e += 256) {
            int d = e >> 6, j = e & 63;
            dst[j * DD + d] = src[e];
        }
    } else {
        for (int e = threadIdx.x; e < TSPAN1 * DD; e += 256) {
            int t = e >> 6, d = e & 63;
            tKT[d * TSPAN1 + t] = tK_emb[e];
        }
    }
}

// Layer-0 entry + fused qt: 4 rows/block, wave per row. Embedding fused.
__global__ void ln_qkv_kernel(const int* __restrict__ log_ids,
                              const float* __restrict__ item_emb,
                              const float* __restrict__ g,
                              const float* __restrict__ bln,
                              const float* __restrict__ WqT, const float* __restrict__ bq,
                              const float* __restrict__ WkT, const float* __restrict__ bk,
                              const float* __restrict__ WvT, const float* __restrict__ bv,
                              const float* __restrict__ posK,
                              const float* __restrict__ posV,
                              const float* __restrict__ tKT,
                              float* __restrict__ q,
                              float* __restrict__ Q, float* __restrict__ K,
                              float* __restrict__ V,
                              unsigned short* __restrict__ Qt_g) {
    __shared__ float qs[4][DD], xs[4][DD], Qsh[4][DD];
    int tid = threadIdx.x;
    int wid = tid >> 6, d = tid & 63;
    int row = blockIdx.x * 4 + wid;
    int l = row % LLEN;
    int id = log_ids[row];
    float xv = (id == 0) ? 0.0f : item_emb[(size_t)id * DD + d] * 8.0f;  // sqrt(64)*keep
    xs[wid][d] = xv;
    float m = waveSum(xv) * (1.0f / 64.0f);
    float c = xv - m;
    float var = waveSum(c * c) * (1.0f / 64.0f);
    float qv = (c / sqrtf(var + 1e-8f)) * g[d] + bln[d];
    qs[wid][d] = qv;
    q[(size_t)row * DD + d] = qv;
    float aq = bq[d], ak = bk[d], av = bv[d];
#pragma unroll 8
    for (int j = 0; j < DD; ++j) {
        aq = fmaf(qs[wid][j], WqT[j * DD + d], aq);
        ak = fmaf(xs[wid][j], WkT[j * DD + d], ak);
        av = fmaf(xs[wid][j], WvT[j * DD + d], av);
    }
    Q[(size_t)row * DD + d] = aq;
    K[(size_t)row * DD + d] = ak + posK[l * DD + d];
    V[(size_t)row * DD + d] = av + posV[l * DD + d];
    Qsh[wid][d] = aq;
    __syncthreads();
    qt_tail(Qsh, tKT, Qt_g, blockIdx.x * 4);
}

// Attention (R9 structure; qt in bf16). wave-per-query {i,99-i,100+i,199-i};
// per-wave phases; qt_s staged (bf16, uint2 loads); 4-key score groups.
__global__ void attn_kernel(const float* __restrict__ Q,
                            const float* __restrict__ Keff,
                            const float* __restrict__ Veff,
                            const int* __restrict__ log_times,
                            const unsigned short* __restrict__ Qt_g,
                            const float* __restrict__ tV_emb,
                            float* __restrict__ out) {
    __shared__ int t_s[LLEN];
    __shared__ float sc[4][HH][LLEN];
    __shared__ unsigned short tm_s[4][LLEN];
    __shared__ __align__(8) unsigned short qt_s[4][QTROW];

    int tid = threadIdx.x;
    int wid = tid >> 6;
    int lane = tid & 63;
    int bi = blockIdx.x / 50;
    int i = blockIdx.x % 50;
    int qi = (wid == 0) ? i : (wid == 1) ? (99 - i) : (wid == 2) ? (100 + i) : (199 - i);
    int row = bi * LLEN + qi;
    int len = qi + 1;

    if (tid < LLEN) t_s[tid] = log_times[bi * LLEN + tid];
    __syncthreads();

    // stage this query's Qt row (732 bf16 = 183 uint2) into LDS
    {
        const uint2* qtrow2 = (const uint2*)(Qt_g + (size_t)row * QTROW);
        uint2* qts2 = (uint2*)&qt_s[wid][0];
        for (int e = lane; e < 183; e += 64) qts2[e] = qtrow2[e];
    }

    // bucket table for this query
    int tq = t_s[qi];
    for (int k = lane; k < len; k += 64) {
        int dt = tq - t_s[k];
        if (dt < 0) dt = -dt;
        float dtf = fminf((float)dt * (1.0f / 86400.0f), 365.0f);
        tm_s[wid][k] = (unsigned short)(int)dtf;
    }

    int h = lane >> 5;       // head
    int l5 = lane & 31;
    int cch = l5 >> 2;       // channel chunk 0..7
    int jo = l5 & 3;         // key offset in group
    float4 qv = ((const float4*)(Q + (size_t)row * DD))[h * 8 + cch];
    const float4* K4 = (const float4*)(Keff + (size_t)bi * LLEN * DD);
    const float scale = 0.17677669529663687f;  // 1/sqrt(32)

    // phase 1: scores, 4 keys per iteration
    for (int k0 = 0; k0 < len; k0 += 4) {
        int k = k0 + jo;
        int kc = (k < len) ? k : (len - 1);
        int bucket = tm_s[wid][kc];
        float4 kv = K4[kc * 16 + h * 8 + cch];
        float p = qv.x * kv.x + qv.y * kv.y + qv.z * kv.z + qv.w * kv.w;
        p += __shfl_xor(p, 4);
        p += __shfl_xor(p, 8);
        p += __shfl_xor(p, 16);   // full 32-dot for (h, key k)
        float s = (p + bf2f(qt_s[wid][h * TSPAN1 + bucket])) * scale;
        if (cch == 0 && k < len) sc[wid][h][k] = s;
    }

    // phase 2: softmax (lanes 0..31 head 0, 32..63 head 1; same wave)
    {
        float m = -INFINITY;
        for (int k = l5; k < len; k += 32) m = fmaxf(m, sc[wid][h][k]);
        m = halfMax(m);
        float s = 0.0f;
        for (int k = l5; k < len; k += 32) {
            float e = expf(sc[wid][h][k] - m);
            sc[wid][h][k] = e;
            s += e;
        }
        s = halfSum(s);
        float inv = 1.0f / s;
        for (int k = l5; k < len; k += 32) sc[wid][h][k] *= inv;
    }

    // phase 3: out[d] = sum_k A[h][k] * (V_eff[k][d] + tV[bucket[k]][d])
    const float* Vb = Veff + (size_t)bi * LLEN * DD + lane;
    const float* tVl = tV_emb + lane;
    float acc0 = 0.0f, acc1 = 0.0f, acc2 = 0.0f, acc3 = 0.0f;
    int k = 0;
    for (; k + 4 <= len; k += 4) {
        int b0 = tm_s[wid][k + 0];
        int b1 = tm_s[wid][k + 1];
        int b2 = tm_s[wid][k + 2];
        int b3 = tm_s[wid][k + 3];
        float a0 = sc[wid][h][k + 0];
        float a1 = sc[wid][h][k + 1];
        float a2 = sc[wid][h][k + 2];
        float a3 = sc[wid][h][k + 3];
        acc0 = fmaf(a0, Vb[(k + 0) * DD] + tVl[b0 * DD], acc0);
        acc1 = fmaf(a1, Vb[(k + 1) * DD] + tVl[b1 * DD], acc1);
        acc2 = fmaf(a2, Vb[(k + 2) * DD] + tVl[b2 * DD], acc2);
        acc3 = fmaf(a3, Vb[(k + 3) * DD] + tVl[b3 * DD], acc3);
    }
    for (; k < len; ++k) {
        int b0 = tm_s[wid][k];
        acc0 = fmaf(sc[wid][h][k], Vb[k * DD] + tVl[b0 * DD], acc0);
    }
    out[(size_t)row * DD + lane] = (acc0 + acc1) + (acc2 + acc3);
}

// MID + fused qt: addln_ffn(layer i) + ln_qkv(layer i+1) + qt tail.
__global__ void mid_kernel(const float* __restrict__ qin,
                           const float* __restrict__ att,
                           const float* __restrict__ g2, const float* __restrict__ b2ln,
                           const float* __restrict__ W1T, const float* __restrict__ b1v,
                           const float* __restrict__ W2T, const float* __restrict__ b2v,
                           const int* __restrict__ log_ids,
                           const float* __restrict__ g1n, const float* __restrict__ b1n,
                           const float* __restrict__ WqT, const float* __restrict__ bq,
                           const float* __restrict__ WkT, const float* __restrict__ bk,
                           const float* __restrict__ WvT, const float* __restrict__ bv,
                           const float* __restrict__ posK,
                           const float* __restrict__ posV,
                           const float* __restrict__ tKT,
                           float* __restrict__ q,
                           float* __restrict__ Q, float* __restrict__ K,
                           float* __restrict__ V,
                           unsigned short* __restrict__ Qt_g) {
    __shared__ float xs[4][DD], hs[4][DD], qs[4][DD], Qsh[4][DD];
    int tid = threadIdx.x;
    int wid = tid >> 6, d = tid & 63;
    int row = blockIdx.x * 4 + wid;
    int l = row % LLEN;
    // --- addln + FFN ---
    float v = qin[(size_t)row * DD + d] + att[(size_t)row * DD + d];
    float m = waveSum(v) * (1.0f / 64.0f);
    float c = v - m;
    float var = waveSum(c * c) * (1.0f / 64.0f);
    float xv = (c / sqrtf(var + 1e-8f)) * g2[d] + b2ln[d];
    xs[wid][d] = xv;
    float a = b1v[d];
#pragma unroll 8
    for (int j = 0; j < DD; ++j) a = fmaf(xs[wid][j], W1T[j * DD + d], a);
    hs[wid][d] = fmaxf(a, 0.0f);
    float o = b2v[d];
#pragma unroll 8
    for (int j = 0; j < DD; ++j) o = fmaf(hs[wid][j], W2T[j * DD + d], o);
    float res = xv + o;
    if (log_ids[row] == 0) res = 0.0f;
    // --- next layer: LN1 + QKV projection ---
    float m2 = waveSum(res) * (1.0f / 64.0f);
    float c2 = res - m2;
    float var2 = waveSum(c2 * c2) * (1.0f / 64.0f);
    float qv = (c2 / sqrtf(var2 + 1e-8f)) * g1n[d] + b1n[d];
    qs[wid][d] = qv;
    xs[wid][d] = res;
    q[(size_t)row * DD + d] = qv;
    float aq = bq[d], ak = bk[d], av = bv[d];
#pragma unroll 8
    for (int j = 0; j < DD; ++j) {
        aq = fmaf(qs[wid][j], WqT[j * DD + d], aq);
        ak = fmaf(xs[wid][j], WkT[j * DD + d], ak);
        av = fmaf(xs[wid][j], WvT[j * DD + d], av);
    }
    Q[(size_t)row * DD + d] = aq;
    K[(size_t)row * DD + d] = ak + posK[l * DD + d];
    V[(size_t)row * DD + d] = av + posV[l * DD + d];
    Qsh[wid][d] = aq;
    __syncthreads();
    qt_tail(Qsh, tKT, Qt_g, blockIdx.x * 4);
}

// END: addln_ffn(last layer) fused with final LN + logits. 4 rows/block.
__global__ void end_kernel(const float* __restrict__ qin,
                           const float* __restrict__ att,
                           const float* __restrict__ g2, const float* __restrict__ b2ln,
                           const float* __restrict__ W1T, const float* __restrict__ b1v,
                           const float* __restrict__ W2T, const float* __restrict__ b2v,
                           const int* __restrict__ log_ids,
                           const float* __restrict__ lnf_g, const float* __restrict__ lnf_b,
                           const float* __restrict__ item_emb,
                           const int* __restrict__ pos_ids,
                           const int* __restrict__ neg_ids,
                           float* __restrict__ out) {
    __shared__ float xs[4][DD], hs[4][DD];
    int tid = threadIdx.x;
    int wid = tid >> 6, d = tid & 63;
    int row = blockIdx.x * 4 + wid;
    float v = qin[(size_t)row * DD + d] + att[(size_t)row * DD + d];
    float m = waveSum(v) * (1.0f / 64.0f);
    float c = v - m;
    float var = waveSum(c * c) * (1.0f / 64.0f);
    float xv = (c / sqrtf(var + 1e-8f)) * g2[d] + b2ln[d];
    xs[wid][d] = xv;
    float a = b1v[d];
#pragma unroll 8
    for (int j = 0; j < DD; ++j) a = fmaf(xs[wid][j], W1T[j * DD + d], a);
    hs[wid][d] = fmaxf(a, 0.0f);
    float o = b2v[d];
#pragma unroll 8
    for (int j = 0; j < DD; ++j) o = fmaf(hs[wid][j], W2T[j * DD + d], o);
    float res = xv + o;
    if (log_ids[row] == 0) res = 0.0f;
    // --- final LN + logits ---
    float m2 = waveSum(res) * (1.0f / 64.0f);
    float c2 = res - m2;
    float var2 = waveSum(c2 * c2) * (1.0f / 64.0f);
    float f = (c2 / sqrtf(var2 + 1e-8f)) * lnf_g[d] + lnf_b[d];
    int pid = pos_ids[row];
    int nid = neg_ids[row];
    float p = waveSum(f * item_emb[(size_t)pid * DD + d]);
    float n = waveSum(f * item_emb[(size_t)nid * DD + d]);
    if (d == 0) {
        out[row] = p;
        out[BB * LLEN + row] = n;
    }
}

extern "C" void kernel_launch(void* const* d_in, const int* in_sizes, int n_in,
                              void* d_out, int out_size, void* d_ws, size_t ws_size,
                              hipStream_t stream) {
    const int* log_ids = (const int*)d_in[0];
    const int* log_times = (const int*)d_in[1];
    const int* pos_ids = (const int*)d_in[2];
    const int* neg_ids = (const int*)d_in[3];
    const float* item_emb = (const float*)d_in[4];
    const float* posK = (const float*)d_in[5];
    const float* posV = (const float*)d_in[6];
    const float* tK_emb = (const float*)d_in[7];
    const float* tV_emb = (const float*)d_in[8];
    const float* ln1_g = (const float*)d_in[9];
    const float* ln1_b = (const float*)d_in[10];
    const float* Wq = (const float*)d_in[11];
    const float* bq = (const float*)d_in[12];
    const float* Wk = (const float*)d_in[13];
    const float* bk = (const float*)d_in[14];
    const float* Wv = (const float*)d_in[15];
    const float* bv = (const float*)d_in[16];
    const float* ln2_g = (const float*)d_in[17];
    const float* ln2_b = (const float*)d_in[18];
    const float* W1 = (const float*)d_in[19];
    const float* b1 = (const float*)d_in[20];
    const float* W2 = (const float*)d_in[21];
    const float* b2 = (const float*)d_in[22];
    const float* lnf_g = (const float*)d_in[23];
    const float* lnf_b = (const float*)d_in[24];

    float* ws = (float*)d_ws;
    float* q = ws;                        // ln1 output (residual)
    float* Qb = q + BLD;
    float* Kb = Qb + BLD;
    float* Vb = Kb + BLD;
    float* att = Vb + BLD;
    float* wt = att + BLD;                // 10 x 64x64 transposed weights
    float* tKT = wt + 10 * DD * DD;       // [64][366]
    unsigned short* Qt = (unsigned short*)(tKT + DD * TSPAN1);  // [6400][732] bf16

    const int nrow = BB * LLEN;           // 6400

    const float* W1T0 = wt + 3 * DD * DD;
    const float* W2T0 = wt + 4 * DD * DD;
    const float* W1T1 = wt + 8 * DD * DD;
    const float* W2T1 = wt + 9 * DD * DD;

    transpose_kernel<<<11, 256, 0, stream>>>(Wq, Wk, Wv, W1, W2, tK_emb, wt, tKT);

    // layer 0 entry (embed + qt fused)
    ln_qkv_kernel<<<nrow / 4, 256, 0, stream>>>(log_ids, item_emb,
                                                ln1_g, ln1_b,
                                                wt + 0 * DD * DD, bq,
                                                wt + 1 * DD * DD, bk,
                                                wt + 2 * DD * DD, bv,
                                                posK, posV, tKT,
                                                q, Qb, Kb, Vb, Qt);
    attn_kernel<<<BB * 50, 256, 0, stream>>>(Qb, Kb, Vb, log_times, Qt, tV_emb, att);

    // layer 0 tail + layer 1 entry (+ qt fused)
    mid_kernel<<<nrow / 4, 256, 0, stream>>>(q, att,
                                             ln2_g, ln2_b,
                                             W1T0, b1, W2T0, b2,
                                             log_ids,
                                             ln1_g + DD, ln1_b + DD,
                                             wt + 5 * DD * DD, bq + DD,
                                             wt + 6 * DD * DD, bk + DD,
                                             wt + 7 * DD * DD, bv + DD,
                                             posK, posV, tKT,
                                             q, Qb, Kb, Vb, Qt);
    attn_kernel<<<BB * 50, 256, 0, stream>>>(Qb, Kb, Vb, log_times, Qt, tV_emb, att);

    // layer 1 tail + final logits
    end_kernel<<<nrow / 4, 256, 0, stream>>>(q, att,
                                             ln2_g + DD, ln2_b + DD,
                                             W1T1, b1 + DD, W2T1, b2 + DD,
                                             log_ids,
                                             lnf_g, lnf_b, item_emb,
                                             pos_ids, neg_ids, (float*)d_out);
}